// Round 9
// baseline (293.610 us; speedup 1.0000x reference)
//
#include <hip/hip_runtime.h>
#include <math.h>

// ---------------------------------------------------------------------------
// Round 9: vectorized-epilogue x-path (swapped MFMA operands), spatial ao,
// 64KB 2-phase weight staging, 2 blocks/CU.
//   prep:  proj_w/mw1/mw2 fp32->bf16 ; bias_table -> biasPb bf16
//   A: ln_qkv -> qw/kw/vw bf16 window layout
//   B: attn per (window,head) -> ao bf16 SPATIAL layout [65536][256]
//   P: proj + bias + residual(v) + LN2 -> xbf, xln (bf16 spatial)
//   M1: mlp1-half + GELU -> h1 [65536][512]
//   M2: mlp2 oc-half + bias + residual(xbf) -> out (fp32 spatial)
// P/M1/M2: swapped operands => lane holds (token fixed, 4 consecutive oc):
// all epilogue traffic is float4 / shortx4. Wave = 16 tokens x all cols,
// acc <= 64 VGPR, launch_bounds(512,4), LDS 64KB => 2 blocks/CU.
//
// Workspace (unchanged from R8):
//   qw[0,32M) kw[32M,64M) vw[64M,96M) ao[96M,128M)   (byte offsets below)
//   xln over qw, xbf over kw, h1 over vw+ao
//   wp/w1/w2/biasPb at 160M+.
// ---------------------------------------------------------------------------

typedef __attribute__((ext_vector_type(8))) short short8;
typedef __attribute__((ext_vector_type(4))) short shortx4;
typedef __attribute__((ext_vector_type(4))) float floatx4;

#define MFMA16(a, b, c) __builtin_amdgcn_mfma_f32_16x16x32_bf16((a), (b), (c), 0, 0, 0)
#define ATT_SCALE 0.17677669529663689f /* 32^-0.5 */

__device__ __forceinline__ short f2bf(float f) {
  unsigned u = __float_as_uint(f);
  u += 0x7fffu + ((u >> 16) & 1u);
  return (short)(u >> 16);
}
__device__ __forceinline__ float bf2f(short s) {
  return __uint_as_float(((unsigned)(unsigned short)s) << 16);
}

// ---------------------------------------------------------------------------
// prep kernels
// ---------------------------------------------------------------------------
__global__ void cvt_kernel(const float* __restrict__ src, short* __restrict__ dst, int n) {
  int i = blockIdx.x * 256 + threadIdx.x;
  if (i < n) dst[i] = f2bf(src[i]);
}

__global__ void biasprep_kernel(const float* __restrict__ table, short* __restrict__ biasPb) {
  int idx = blockIdx.x * 256 + threadIdx.x;  // [0, 131072)
  int h = idx >> 14;
  int n = (idx >> 7) & 127;
  int lr = (idx >> 3) & 15;
  int c = idx & 7;
  int m = 16 * c + lr;
  int t1 = n >> 6, h1 = (n >> 3) & 7, w1 = n & 7;
  int t2 = m >> 6, h2 = (m >> 3) & 7, w2 = m & 7;
  int ridx = (t1 - t2 + 1) * 225 + (h1 - h2 + 7) * 15 + (w1 - w2 + 7);
  biasPb[idx] = f2bf(table[ridx * 8 + h]);
}

// ---------------------------------------------------------------------------
// Kernel A: LN + window partition, fp32 -> bf16 window layout. One wave/token.
// ---------------------------------------------------------------------------
__global__ __launch_bounds__(256) void ln_qkv_kernel(
    const float* __restrict__ q, const float* __restrict__ k, const float* __restrict__ v,
    const float* __restrict__ gq, const float* __restrict__ bq,
    const float* __restrict__ gk, const float* __restrict__ bk,
    const float* __restrict__ gv, const float* __restrict__ bv,
    short* __restrict__ qw, short* __restrict__ kw, short* __restrict__ vw) {
  const int wv = threadIdx.x >> 6, l = threadIdx.x & 63;
  const int tok = blockIdx.x * 4 + wv;
  const int which = blockIdx.y;
  const float* src = (which == 0) ? q : ((which == 1) ? k : v);
  const float* gg  = (which == 0) ? gq : ((which == 1) ? gk : gv);
  const float* bb  = (which == 0) ? bq : ((which == 1) ? bk : bv);
  short* dst       = (which == 0) ? qw : ((which == 1) ? kw : vw);

  float4 xv = *(const float4*)(src + (size_t)tok * 256 + l * 4);
  float s1 = xv.x + xv.y + xv.z + xv.w;
  float s2 = xv.x * xv.x + xv.y * xv.y + xv.z * xv.z + xv.w * xv.w;
#pragma unroll
  for (int off = 1; off < 64; off <<= 1) {
    s1 += __shfl_xor(s1, off);
    s2 += __shfl_xor(s2, off);
  }
  float mean = s1 * (1.0f / 256.0f);
  float var = s2 * (1.0f / 256.0f) - mean * mean;
  float inv = rsqrtf(var + 1e-5f);

  int b_ = tok >> 15, rem = tok & 32767;
  int t = rem >> 12, hh = (rem >> 6) & 63, ww = rem & 63;
  int wi = ((b_ * 4 + (t >> 1)) * 8 + (hh >> 3)) * 8 + (ww >> 3);
  int n = ((t & 1) << 6) | ((hh & 7) << 3) | (ww & 7);

  float4 g4 = *(const float4*)(gg + l * 4);
  float4 b4 = *(const float4*)(bb + l * 4);
  shortx4 o;
  o[0] = f2bf((xv.x - mean) * inv * g4.x + b4.x);
  o[1] = f2bf((xv.y - mean) * inv * g4.y + b4.y);
  o[2] = f2bf((xv.z - mean) * inv * g4.z + b4.z);
  o[3] = f2bf((xv.w - mean) * inv * g4.w + b4.w);
  *(shortx4*)(dst + ((size_t)wi * 128 + n) * 256 + l * 4) = o;
}

// ---------------------------------------------------------------------------
// Kernel B: windowed attention, one block per (window, head), 4 waves, 40KB LDS.
// ao written in SPATIAL token order.
// ---------------------------------------------------------------------------
__global__ __launch_bounds__(256, 4) void attn_kernel(
    const short* __restrict__ qw, const short* __restrict__ kw, const short* __restrict__ vw,
    const short* __restrict__ biasPb, short* __restrict__ ao) {
  __shared__ union SU {
    struct { short Qs[128][40]; short Ks[128][40]; } qk;
    short Ps[128 * 128];  // XOR-swizzled
  } su;
  __shared__ short Vt[32 * 128];  // V^T, XOR-swizzled

  const int wi = blockIdx.x, h = blockIdx.y, tid = threadIdx.x;
  const size_t base = (size_t)wi * 128 * 256 + h * 32;

#pragma unroll
  for (int i = 0; i < 2; ++i) {
    int idx = tid + 256 * i;        // 0..511
    int m = idx >> 2, c = idx & 3;  // token row, 8-elem unit
    *(short8*)&su.qk.Qs[m][c * 8] = *(const short8*)(qw + base + (size_t)m * 256 + c * 8);
    *(short8*)&su.qk.Ks[m][c * 8] = *(const short8*)(kw + base + (size_t)m * 256 + c * 8);
    short8 vv = *(const short8*)(vw + base + (size_t)m * 256 + c * 8);
#pragma unroll
    for (int e = 0; e < 8; ++e) {
      int d = c * 8 + e;
      Vt[d * 128 + (((m >> 3) ^ (d & 7)) << 3) + (m & 7)] = vv[e];
    }
  }
  __syncthreads();

  const int wvv = tid >> 6, l = tid & 63, lr = l & 15, g = l >> 4;
  const floatx4 zf = {0.f, 0.f, 0.f, 0.f};

  short8 aq0 = *(const short8*)&su.qk.Qs[32 * wvv + lr][g * 8];
  short8 aq1 = *(const short8*)&su.qk.Qs[32 * wvv + 16 + lr][g * 8];

  floatx4 s[2][8];
#pragma unroll
  for (int c = 0; c < 8; ++c) {
    short8 bk8 = *(const short8*)&su.qk.Ks[16 * c + lr][g * 8];
    s[0][c] = MFMA16(aq0, bk8, zf);
    s[1][c] = MFMA16(aq1, bk8, zf);
  }
  __syncthreads();  // Qs/Ks dead -> Ps region reusable

  const int lr7 = lr & 7;
#pragma unroll
  for (int r = 0; r < 2; ++r) {
#pragma unroll
    for (int j = 0; j < 4; ++j) {
      int n = 32 * wvv + 16 * r + 4 * g + j;
      short8 bv8 = *(const short8*)(biasPb + ((size_t)(h * 128 + n) * 16 + lr) * 8);
      float mx = -1e30f;
#pragma unroll
      for (int c = 0; c < 8; ++c) {
        float val = s[r][c][j] * ATT_SCALE + bf2f(bv8[c]);
        s[r][c][j] = val;
        mx = fmaxf(mx, val);
      }
#pragma unroll
      for (int off = 1; off < 16; off <<= 1) mx = fmaxf(mx, __shfl_xor(mx, off));
      float sum = 0.f;
#pragma unroll
      for (int c = 0; c < 8; ++c) {
        float e = __expf(s[r][c][j] - mx);
        s[r][c][j] = e;
        sum += e;
      }
#pragma unroll
      for (int off = 1; off < 16; off <<= 1) sum += __shfl_xor(sum, off);
      float invs = 1.0f / sum;
      int n7 = n & 7;
#pragma unroll
      for (int c = 0; c < 8; ++c) {
        int col = 16 * c + lr;
        su.Ps[n * 128 + (((col >> 3) ^ n7) << 3) + (col & 7)] = f2bf(s[r][c][j] * invs);
      }
    }
  }
  // each wave reads only its own 32 P rows below -> no barrier

  floatx4 o00 = zf, o01 = zf, o10 = zf, o11 = zf;
  const int ra0 = 32 * wvv + lr, ra1 = ra0 + 16;
#pragma unroll
  for (int ks = 0; ks < 4; ++ks) {
    int ulog = ks * 4 + g;
    short8 pa0 = *(const short8*)&su.Ps[ra0 * 128 + ((ulog ^ (ra0 & 7)) << 3)];
    short8 pa1 = *(const short8*)&su.Ps[ra1 * 128 + ((ulog ^ (ra1 & 7)) << 3)];
    short8 vb0 = *(const short8*)&Vt[lr * 128 + ((ulog ^ lr7) << 3)];
    short8 vb1 = *(const short8*)&Vt[(16 + lr) * 128 + ((ulog ^ lr7) << 3)];
    o00 = MFMA16(pa0, vb0, o00);
    o01 = MFMA16(pa0, vb1, o01);
    o10 = MFMA16(pa1, vb0, o10);
    o11 = MFMA16(pa1, vb1, o11);
  }
  // spatial scatter of ao
  const int wbx = wi & 7, hbx = (wi >> 3) & 7, ttx = (wi >> 6) & 3, bbx = wi >> 8;
#pragma unroll
  for (int j = 0; j < 4; ++j) {
    int n0 = 32 * wvv + 4 * g + j;
    int n1 = n0 + 16;
    int t0 = ttx * 2 + (n0 >> 6), hh0 = hbx * 8 + ((n0 >> 3) & 7), ww0 = wbx * 8 + (n0 & 7);
    int t1 = ttx * 2 + (n1 >> 6), hh1 = hbx * 8 + ((n1 >> 3) & 7), ww1 = wbx * 8 + (n1 & 7);
    size_t rb0 = (((size_t)(bbx * 8 + t0) * 64 + hh0) * 64 + ww0) * 256 + h * 32;
    size_t rb1 = (((size_t)(bbx * 8 + t1) * 64 + hh1) * 64 + ww1) * 256 + h * 32;
    ao[rb0 + lr] = f2bf(o00[j]);
    ao[rb0 + 16 + lr] = f2bf(o01[j]);
    ao[rb1 + lr] = f2bf(o10[j]);
    ao[rb1 + 16 + lr] = f2bf(o11[j]);
  }
}

// ---------------------------------------------------------------------------
// Kernel P: proj + bias + residual(v) + LN2, swapped operands, spatial.
// 512 blocks x 512 thr; wave = 16 tokens x 256 oc; WS 64KB (2 k-phases).
// Lane: token = bx*128 + w*16 + lr (fixed); oc = ct*16 + 4g + j.
// ---------------------------------------------------------------------------
__global__ __launch_bounds__(512, 4) void projln_kernel(
    const short* __restrict__ ao, const short* __restrict__ wp,
    const float* __restrict__ proj_b, const float* __restrict__ vin,
    const float* __restrict__ g2, const float* __restrict__ b2,
    short* __restrict__ xbf, short* __restrict__ xln) {
  __shared__ short WS[256 * 128];  // 64KB: [oc row][16 units], swz u^(r&7)

  const int tid = threadIdx.x;
  const int w = tid >> 6, l = tid & 63, lr = l & 15, g = l >> 4;
  const floatx4 zf = {0.f, 0.f, 0.f, 0.f};
  const size_t token = (size_t)blockIdx.x * 128 + w * 16 + lr;

  floatx4 acc[16];
#pragma unroll
  for (int i = 0; i < 16; ++i) acc[i] = zf;

#pragma unroll
  for (int ph = 0; ph < 2; ++ph) {
    if (ph) __syncthreads();  // prior phase's WS reads retired
#pragma unroll
    for (int c = 0; c < 8; ++c) {
      int idx = tid * 8 + c;  // 0..4095 units
      int r = idx >> 4, u = idx & 15;
      short8 vv = *(const short8*)(wp + (size_t)r * 256 + ph * 128 + u * 8);
      *(short8*)&WS[r * 128 + ((u ^ (r & 7)) << 3)] = vv;
    }
    __syncthreads();
    short8 a[4];
#pragma unroll
    for (int s = 0; s < 4; ++s)
      a[s] = *(const short8*)(ao + token * 256 + ph * 128 + s * 32 + g * 8);
#pragma unroll
    for (int s = 0; s < 4; ++s) {
#pragma unroll
      for (int ct = 0; ct < 16; ++ct) {
        int rb = ct * 16 + lr;
        short8 wf = *(const short8*)&WS[rb * 128 + (((s * 4 + g) ^ (rb & 7)) << 3)];
        acc[ct] = MFMA16(wf, a[s], acc[ct]);
      }
    }
  }

  // epilogue: x = acc + pb + vin (float4); LN2 (in-lane + 2 shfl); stores 8B
  float s1 = 0.f, s2 = 0.f;
#pragma unroll
  for (int ct = 0; ct < 16; ++ct) {
    float4 pb = *(const float4*)(proj_b + ct * 16 + 4 * g);
    float4 vv = *(const float4*)(vin + token * 256 + ct * 16 + 4 * g);
#pragma unroll
    for (int j = 0; j < 4; ++j) {
      float val = acc[ct][j] + ((const float*)&pb)[j] + ((const float*)&vv)[j];
      acc[ct][j] = val;
      s1 += val;
      s2 += val * val;
    }
  }
  s1 += __shfl_xor(s1, 16); s1 += __shfl_xor(s1, 32);
  s2 += __shfl_xor(s2, 16); s2 += __shfl_xor(s2, 32);
  float mean = s1 * (1.0f / 256.0f);
  float var = s2 * (1.0f / 256.0f) - mean * mean;
  float inv = rsqrtf(var + 1e-5f);
#pragma unroll
  for (int ct = 0; ct < 16; ++ct) {
    float4 gg = *(const float4*)(g2 + ct * 16 + 4 * g);
    float4 bb = *(const float4*)(b2 + ct * 16 + 4 * g);
    shortx4 xo, lo;
#pragma unroll
    for (int j = 0; j < 4; ++j) {
      xo[j] = f2bf(acc[ct][j]);
      lo[j] = f2bf((acc[ct][j] - mean) * inv * ((const float*)&gg)[j] + ((const float*)&bb)[j]);
    }
    *(shortx4*)(xbf + token * 256 + ct * 16 + 4 * g) = xo;
    *(shortx4*)(xln + token * 256 + ct * 16 + 4 * g) = lo;
  }
}

// ---------------------------------------------------------------------------
// Kernel M1: mlp1 half + GELU, swapped operands. Grid (512, 2) x 512 thr.
// ---------------------------------------------------------------------------
__global__ __launch_bounds__(512, 4) void mlp1_kernel(
    const short* __restrict__ xln, const short* __restrict__ w1,
    const float* __restrict__ mb1, short* __restrict__ h1) {
  __shared__ short WS[256 * 128];  // 64KB

  const int tid = threadIdx.x;
  const int w = tid >> 6, l = tid & 63, lr = l & 15, g = l >> 4;
  const int half = blockIdx.y;
  const floatx4 zf = {0.f, 0.f, 0.f, 0.f};
  const short* w1h = w1 + (size_t)half * 256 * 256;
  const size_t token = (size_t)blockIdx.x * 128 + w * 16 + lr;

  floatx4 acc[16];
#pragma unroll
  for (int i = 0; i < 16; ++i) acc[i] = zf;

#pragma unroll
  for (int ph = 0; ph < 2; ++ph) {
    if (ph) __syncthreads();
#pragma unroll
    for (int c = 0; c < 8; ++c) {
      int idx = tid * 8 + c;
      int r = idx >> 4, u = idx & 15;
      short8 vv = *(const short8*)(w1h + (size_t)r * 256 + ph * 128 + u * 8);
      *(short8*)&WS[r * 128 + ((u ^ (r & 7)) << 3)] = vv;
    }
    __syncthreads();
    short8 a[4];
#pragma unroll
    for (int s = 0; s < 4; ++s)
      a[s] = *(const short8*)(xln + token * 256 + ph * 128 + s * 32 + g * 8);
#pragma unroll
    for (int s = 0; s < 4; ++s) {
#pragma unroll
      for (int ct = 0; ct < 16; ++ct) {
        int rb = ct * 16 + lr;
        short8 wf = *(const short8*)&WS[rb * 128 + (((s * 4 + g) ^ (rb & 7)) << 3)];
        acc[ct] = MFMA16(wf, a[s], acc[ct]);
      }
    }
  }

#pragma unroll
  for (int ct = 0; ct < 16; ++ct) {
    float4 bb = *(const float4*)(mb1 + half * 256 + ct * 16 + 4 * g);
    shortx4 ho;
#pragma unroll
    for (int j = 0; j < 4; ++j) {
      float xv = acc[ct][j] + ((const float*)&bb)[j];
      float yy = 1.5957691216057308f * (xv + 0.044715f * xv * xv * xv);
      float sg = 1.0f / (1.0f + __expf(-yy));
      ho[j] = f2bf(xv * sg);
    }
    *(shortx4*)(h1 + token * 512 + half * 256 + ct * 16 + 4 * g) = ho;
  }
}

// ---------------------------------------------------------------------------
// Kernel M2: mlp2 oc-half + bias + residual(xbf), swapped operands.
// Grid (512, 2) x 512 thr. WS[128 oc][256 k] = 64KB, 2 k-phases (K=512).
// ---------------------------------------------------------------------------
__global__ __launch_bounds__(512, 4) void mlp2_kernel(
    const short* __restrict__ h1, const short* __restrict__ w2,
    const float* __restrict__ mb2, const short* __restrict__ xbf,
    float* __restrict__ out) {
  __shared__ short WS[128 * 256];  // 64KB: [oc row][32 units], swz u^(r&7)

  const int tid = threadIdx.x;
  const int w = tid >> 6, l = tid & 63, lr = l & 15, g = l >> 4;
  const int half = blockIdx.y;
  const floatx4 zf = {0.f, 0.f, 0.f, 0.f};
  const short* w2h = w2 + (size_t)half * 128 * 512;
  const size_t token = (size_t)blockIdx.x * 128 + w * 16 + lr;

  floatx4 acc[8];
#pragma unroll
  for (int i = 0; i < 8; ++i) acc[i] = zf;

#pragma unroll
  for (int ph = 0; ph < 2; ++ph) {
    if (ph) __syncthreads();
#pragma unroll
    for (int c = 0; c < 8; ++c) {
      int idx = tid * 8 + c;  // 0..4095
      int r = idx >> 5, u = idx & 31;
      short8 vv = *(const short8*)(w2h + (size_t)r * 512 + ph * 256 + u * 8);
      *(short8*)&WS[r * 256 + ((u ^ (r & 7)) << 3)] = vv;
    }
    __syncthreads();
    short8 a[8];
#pragma unroll
    for (int s = 0; s < 8; ++s)
      a[s] = *(const short8*)(h1 + token * 512 + ph * 256 + s * 32 + g * 8);
#pragma unroll
    for (int s = 0; s < 8; ++s) {
#pragma unroll
      for (int ct = 0; ct < 8; ++ct) {
        int rb = ct * 16 + lr;
        short8 wf = *(const short8*)&WS[rb * 256 + (((s * 4 + g) ^ (rb & 7)) << 3)];
        acc[ct] = MFMA16(wf, a[s], acc[ct]);
      }
    }
  }

#pragma unroll
  for (int ct = 0; ct < 8; ++ct) {
    int oc = half * 128 + ct * 16 + 4 * g;
    float4 bb = *(const float4*)(mb2 + oc);
    shortx4 xb = *(const shortx4*)(xbf + token * 256 + oc);
    float4 o;
#pragma unroll
    for (int j = 0; j < 4; ++j)
      ((float*)&o)[j] = bf2f(xb[j]) + acc[ct][j] + ((const float*)&bb)[j];
    *(float4*)(out + token * 256 + oc) = o;
  }
}

// ---------------------------------------------------------------------------
extern "C" void kernel_launch(void* const* d_in, const int* in_sizes, int n_in,
                              void* d_out, int out_size, void* d_ws, size_t ws_size,
                              hipStream_t stream) {
  const float* q = (const float*)d_in[0];
  const float* k = (const float*)d_in[1];
  const float* v = (const float*)d_in[2];
  const float* gq = (const float*)d_in[3];
  const float* bq = (const float*)d_in[4];
  const float* gk = (const float*)d_in[5];
  const float* bk = (const float*)d_in[6];
  const float* gv = (const float*)d_in[7];
  const float* bv = (const float*)d_in[8];
  const float* bias_table = (const float*)d_in[9];
  const float* proj_w = (const float*)d_in[10];
  const float* proj_b = (const float*)d_in[11];
  const float* g2 = (const float*)d_in[12];
  const float* b2 = (const float*)d_in[13];
  const float* mw1 = (const float*)d_in[14];
  const float* mb1 = (const float*)d_in[15];
  const float* mw2 = (const float*)d_in[16];
  const float* mb2 = (const float*)d_in[17];

  char* ws = (char*)d_ws;
  short* qw = (short*)(ws + 0);
  short* kw = (short*)(ws + 33554432);
  short* vw = (short*)(ws + 67108864);
  short* ao = (short*)(ws + 100663296);
  short* xln = (short*)(ws + 0);         // over qw (dead after attn)
  short* xbf = (short*)(ws + 33554432);  // over kw (dead after attn)
  short* h1 = (short*)(ws + 67108864);   // over vw+ao (dead after attn / P)
  short* wp = (short*)(ws + 167772160);
  short* w1 = (short*)(ws + 167903232);
  short* w2 = (short*)(ws + 168165376);
  short* biasPb = (short*)(ws + 168427520);

  cvt_kernel<<<256, 256, 0, stream>>>(proj_w, wp, 65536);
  cvt_kernel<<<512, 256, 0, stream>>>(mw1, w1, 131072);
  cvt_kernel<<<512, 256, 0, stream>>>(mw2, w2, 131072);
  biasprep_kernel<<<512, 256, 0, stream>>>(bias_table, biasPb);

  ln_qkv_kernel<<<dim3(16384, 3), 256, 0, stream>>>(q, k, v, gq, bq, gk, bk, gv, bv, qw, kw, vw);

  attn_kernel<<<dim3(512, 8), 256, 0, stream>>>(qw, kw, vw, biasPb, ao);

  projln_kernel<<<512, 512, 0, stream>>>(ao, wp, proj_b, v, g2, b2, xbf, xln);

  mlp1_kernel<<<dim3(512, 2), 512, 0, stream>>>(xln, w1, mb1, h1);

  mlp2_kernel<<<dim3(512, 2), 512, 0, stream>>>(h1, w2, mb2, xbf, (float*)d_out);
}

// Round 10
// 227.785 us; speedup vs baseline: 1.2890x; 1.2890x over previous
//
#include <hip/hip_runtime.h>
#include <math.h>

// ---------------------------------------------------------------------------
// Round 10: occupancy-first x-path. P/M1/M2 use 256-thr blocks + 32KB weight
// panel (pre-packed in LDS-image order -> linear gl2lds) -> 4 blocks/CU.
// Split store streams in P; attn writes ao via LDS re-stage (16B coalesced).
//   prep: packP/pack1/pack2 (weights -> swizzled LDS-image panels), biasprep
//   A: ln_qkv (short8 stores) -> qw/kw/vw bf16 window layout
//   B: attn per (window,head) -> ao bf16 spatial (coalesced stores)
//   P: proj + bias + residual(v) + LN2 -> xbf, xln
//   M1: mlp1-half + GELU -> h1 ; M2: mlp2 + bias + residual -> out
// ---------------------------------------------------------------------------

typedef __attribute__((ext_vector_type(8))) short short8;
typedef __attribute__((ext_vector_type(4))) short shortx4;
typedef __attribute__((ext_vector_type(4))) float floatx4;

#define MFMA16(a, b, c) __builtin_amdgcn_mfma_f32_16x16x32_bf16((a), (b), (c), 0, 0, 0)
#define ATT_SCALE 0.17677669529663689f /* 32^-0.5 */

__device__ __forceinline__ short f2bf(float f) {
  unsigned u = __float_as_uint(f);
  u += 0x7fffu + ((u >> 16) & 1u);
  return (short)(u >> 16);
}
__device__ __forceinline__ float bf2f(short s) {
  return __uint_as_float(((unsigned)(unsigned short)s) << 16);
}
__device__ __forceinline__ void gl2lds(const short* g, short* l) {
  __builtin_amdgcn_global_load_lds((const __attribute__((address_space(1))) void*)(g),
                                   (__attribute__((address_space(3))) void*)(l), 16, 0, 0);
}

// ---------------------------------------------------------------------------
// prep: pack weights into per-phase LDS-image (swizzled) panels, bf16.
// Panel = [256 rows][64 k]; unit us at storage pos = u ^ (r&7).
// ---------------------------------------------------------------------------
__global__ void packP_kernel(const float* __restrict__ w, short* __restrict__ dst) {
  int idx = blockIdx.x * 256 + threadIdx.x;  // 65536 = 4ph x 256r x 64
  int r = (idx >> 6) & 255, us = (idx >> 3) & 7, e = idx & 7;
  int ph = idx >> 14;
  int u = us ^ (r & 7);
  dst[idx] = f2bf(w[r * 256 + ph * 64 + u * 8 + e]);
}
__global__ void pack1_kernel(const float* __restrict__ w, short* __restrict__ dst) {
  int idx = blockIdx.x * 256 + threadIdx.x;  // 131072 = 2hf x 4ph x 256r x 64
  int hf = idx >> 16, ph = (idx >> 14) & 3, r = (idx >> 6) & 255, us = (idx >> 3) & 7, e = idx & 7;
  int u = us ^ (r & 7);
  dst[idx] = f2bf(w[(size_t)(hf * 256 + r) * 256 + ph * 64 + u * 8 + e]);
}
__global__ void pack2_kernel(const float* __restrict__ w, short* __restrict__ dst) {
  int idx = blockIdx.x * 256 + threadIdx.x;  // 131072 = 8ph x 256r x 64
  int ph = idx >> 14, r = (idx >> 6) & 255, us = (idx >> 3) & 7, e = idx & 7;
  int u = us ^ (r & 7);
  dst[idx] = f2bf(w[(size_t)r * 512 + ph * 64 + u * 8 + e]);
}

__global__ void biasprep_kernel(const float* __restrict__ table, short* __restrict__ biasPb) {
  int idx = blockIdx.x * 256 + threadIdx.x;  // [0, 131072)
  int h = idx >> 14;
  int n = (idx >> 7) & 127;
  int lr = (idx >> 3) & 15;
  int c = idx & 7;
  int m = 16 * c + lr;
  int t1 = n >> 6, h1 = (n >> 3) & 7, w1 = n & 7;
  int t2 = m >> 6, h2 = (m >> 3) & 7, w2 = m & 7;
  int ridx = (t1 - t2 + 1) * 225 + (h1 - h2 + 7) * 15 + (w1 - w2 + 7);
  biasPb[idx] = f2bf(table[ridx * 8 + h]);
}

// ---------------------------------------------------------------------------
// Kernel A: LN + window partition. Lane owns 8 ch; 2 rows/wave; short8 stores.
// Grid (8192, 3) x 256.
// ---------------------------------------------------------------------------
__global__ __launch_bounds__(256) void ln_qkv_kernel(
    const float* __restrict__ q, const float* __restrict__ k, const float* __restrict__ v,
    const float* __restrict__ gq, const float* __restrict__ bq,
    const float* __restrict__ gk, const float* __restrict__ bk,
    const float* __restrict__ gv, const float* __restrict__ bv,
    short* __restrict__ qw, short* __restrict__ kw, short* __restrict__ vw) {
  const int wv = threadIdx.x >> 6, l = threadIdx.x & 63;
  const int half = l >> 5, li = l & 31;
  const int tok = blockIdx.x * 8 + wv * 2 + half;
  const int which = blockIdx.y;
  const float* src = (which == 0) ? q : ((which == 1) ? k : v);
  const float* gg  = (which == 0) ? gq : ((which == 1) ? gk : gv);
  const float* bb  = (which == 0) ? bq : ((which == 1) ? bk : bv);
  short* dst       = (which == 0) ? qw : ((which == 1) ? kw : vw);

  float4 x0 = *(const float4*)(src + (size_t)tok * 256 + li * 8);
  float4 x1 = *(const float4*)(src + (size_t)tok * 256 + li * 8 + 4);
  float s1 = x0.x + x0.y + x0.z + x0.w + x1.x + x1.y + x1.z + x1.w;
  float s2 = x0.x * x0.x + x0.y * x0.y + x0.z * x0.z + x0.w * x0.w +
             x1.x * x1.x + x1.y * x1.y + x1.z * x1.z + x1.w * x1.w;
#pragma unroll
  for (int off = 1; off < 32; off <<= 1) {
    s1 += __shfl_xor(s1, off);
    s2 += __shfl_xor(s2, off);
  }
  float mean = s1 * (1.0f / 256.0f);
  float var = s2 * (1.0f / 256.0f) - mean * mean;
  float inv = rsqrtf(var + 1e-5f);

  int b_ = tok >> 15, rem = tok & 32767;
  int t = rem >> 12, hh = (rem >> 6) & 63, ww = rem & 63;
  int wi = ((b_ * 4 + (t >> 1)) * 8 + (hh >> 3)) * 8 + (ww >> 3);
  int n = ((t & 1) << 6) | ((hh & 7) << 3) | (ww & 7);

  float4 g0 = *(const float4*)(gg + li * 8);
  float4 g1 = *(const float4*)(gg + li * 8 + 4);
  float4 b0 = *(const float4*)(bb + li * 8);
  float4 b1 = *(const float4*)(bb + li * 8 + 4);
  short8 o;
  o[0] = f2bf((x0.x - mean) * inv * g0.x + b0.x);
  o[1] = f2bf((x0.y - mean) * inv * g0.y + b0.y);
  o[2] = f2bf((x0.z - mean) * inv * g0.z + b0.z);
  o[3] = f2bf((x0.w - mean) * inv * g0.w + b0.w);
  o[4] = f2bf((x1.x - mean) * inv * g1.x + b1.x);
  o[5] = f2bf((x1.y - mean) * inv * g1.y + b1.y);
  o[6] = f2bf((x1.z - mean) * inv * g1.z + b1.z);
  o[7] = f2bf((x1.w - mean) * inv * g1.w + b1.w);
  *(short8*)(dst + ((size_t)wi * 128 + n) * 256 + li * 8) = o;
}

// ---------------------------------------------------------------------------
// Kernel B: windowed attention, one block per (window, head), 4 waves, 40KB LDS.
// ao written spatially via LDS re-stage (16B coalesced stores).
// ---------------------------------------------------------------------------
__global__ __launch_bounds__(256, 4) void attn_kernel(
    const short* __restrict__ qw, const short* __restrict__ kw, const short* __restrict__ vw,
    const short* __restrict__ biasPb, short* __restrict__ ao) {
  __shared__ union SU {
    struct { short Qs[128][40]; short Ks[128][40]; } qk;
    short Ps[128 * 128];  // XOR-swizzled
  } su;
  __shared__ short Vt[32 * 128];  // V^T, XOR-swizzled; re-used as Ot[128][32]

  const int wi = blockIdx.x, h = blockIdx.y, tid = threadIdx.x;
  const size_t base = (size_t)wi * 128 * 256 + h * 32;

#pragma unroll
  for (int i = 0; i < 2; ++i) {
    int idx = tid + 256 * i;
    int m = idx >> 2, c = idx & 3;
    *(short8*)&su.qk.Qs[m][c * 8] = *(const short8*)(qw + base + (size_t)m * 256 + c * 8);
    *(short8*)&su.qk.Ks[m][c * 8] = *(const short8*)(kw + base + (size_t)m * 256 + c * 8);
    short8 vv = *(const short8*)(vw + base + (size_t)m * 256 + c * 8);
#pragma unroll
    for (int e = 0; e < 8; ++e) {
      int d = c * 8 + e;
      Vt[d * 128 + (((m >> 3) ^ (d & 7)) << 3) + (m & 7)] = vv[e];
    }
  }
  __syncthreads();

  const int wvv = tid >> 6, l = tid & 63, lr = l & 15, g = l >> 4;
  const floatx4 zf = {0.f, 0.f, 0.f, 0.f};

  short8 aq0 = *(const short8*)&su.qk.Qs[32 * wvv + lr][g * 8];
  short8 aq1 = *(const short8*)&su.qk.Qs[32 * wvv + 16 + lr][g * 8];

  floatx4 s[2][8];
#pragma unroll
  for (int c = 0; c < 8; ++c) {
    short8 bk8 = *(const short8*)&su.qk.Ks[16 * c + lr][g * 8];
    s[0][c] = MFMA16(aq0, bk8, zf);
    s[1][c] = MFMA16(aq1, bk8, zf);
  }
  __syncthreads();  // Qs/Ks dead -> Ps region reusable

  const int lr7 = lr & 7;
#pragma unroll
  for (int r = 0; r < 2; ++r) {
#pragma unroll
    for (int j = 0; j < 4; ++j) {
      int n = 32 * wvv + 16 * r + 4 * g + j;
      short8 bv8 = *(const short8*)(biasPb + ((size_t)(h * 128 + n) * 16 + lr) * 8);
      float mx = -1e30f;
#pragma unroll
      for (int c = 0; c < 8; ++c) {
        float val = s[r][c][j] * ATT_SCALE + bf2f(bv8[c]);
        s[r][c][j] = val;
        mx = fmaxf(mx, val);
      }
#pragma unroll
      for (int off = 1; off < 16; off <<= 1) mx = fmaxf(mx, __shfl_xor(mx, off));
      float sum = 0.f;
#pragma unroll
      for (int c = 0; c < 8; ++c) {
        float e = __expf(s[r][c][j] - mx);
        s[r][c][j] = e;
        sum += e;
      }
#pragma unroll
      for (int off = 1; off < 16; off <<= 1) sum += __shfl_xor(sum, off);
      float invs = 1.0f / sum;
      int n7 = n & 7;
#pragma unroll
      for (int c = 0; c < 8; ++c) {
        int col = 16 * c + lr;
        su.Ps[n * 128 + (((col >> 3) ^ n7) << 3) + (col & 7)] = f2bf(s[r][c][j] * invs);
      }
    }
  }
  // each wave reads only its own 32 P rows -> no barrier before PV

  floatx4 o00 = zf, o01 = zf, o10 = zf, o11 = zf;
  const int ra0 = 32 * wvv + lr, ra1 = ra0 + 16;
#pragma unroll
  for (int ks = 0; ks < 4; ++ks) {
    int ulog = ks * 4 + g;
    short8 pa0 = *(const short8*)&su.Ps[ra0 * 128 + ((ulog ^ (ra0 & 7)) << 3)];
    short8 pa1 = *(const short8*)&su.Ps[ra1 * 128 + ((ulog ^ (ra1 & 7)) << 3)];
    short8 vb0 = *(const short8*)&Vt[lr * 128 + ((ulog ^ lr7) << 3)];
    short8 vb1 = *(const short8*)&Vt[(16 + lr) * 128 + ((ulog ^ lr7) << 3)];
    o00 = MFMA16(pa0, vb0, o00);
    o01 = MFMA16(pa0, vb1, o01);
    o10 = MFMA16(pa1, vb0, o10);
    o11 = MFMA16(pa1, vb1, o11);
  }

  __syncthreads();  // all waves done reading Vt -> reuse as Ot[128][32]
  short* Ot = Vt;
#pragma unroll
  for (int j = 0; j < 4; ++j) {
    int n0 = 32 * wvv + 4 * g + j, n1 = n0 + 16;
    Ot[n0 * 32 + lr] = f2bf(o00[j]);
    Ot[n0 * 32 + 16 + lr] = f2bf(o01[j]);
    Ot[n1 * 32 + lr] = f2bf(o10[j]);
    Ot[n1 * 32 + 16 + lr] = f2bf(o11[j]);
  }
  __syncthreads();

  const int wbx = wi & 7, hbx = (wi >> 3) & 7, ttx = (wi >> 6) & 3, bbx = wi >> 8;
#pragma unroll
  for (int c = 0; c < 2; ++c) {
    int i = tid * 2 + c;  // 0..511 = 128 tok x 4 units
    int tok = i >> 2, ui = i & 3;
    int t0 = ttx * 2 + (tok >> 6), hh = hbx * 8 + ((tok >> 3) & 7), ww0 = wbx * 8 + (tok & 7);
    size_t sp = ((size_t)(bbx * 8 + t0) * 64 + hh) * 64 + ww0;
    *(short8*)(ao + sp * 256 + h * 32 + ui * 8) = *(const short8*)&Ot[tok * 32 + ui * 8];
  }
}

// ---------------------------------------------------------------------------
// Kernel P: proj + bias + residual(v) + LN2. 1024 blocks x 256 thr (4 waves).
// WS = one packed 32KB panel/phase; 4 phases; 4 blocks/CU.
// Lane: token = bx*64 + w*16 + lr; oc = ct*16 + 4g + j.
// ---------------------------------------------------------------------------
__global__ __launch_bounds__(256, 4) void projln_kernel(
    const short* __restrict__ ao, const short* __restrict__ wpk,
    const float* __restrict__ proj_b, const float* __restrict__ vin,
    const float* __restrict__ g2, const float* __restrict__ b2,
    short* __restrict__ xbf, short* __restrict__ xln) {
  __shared__ short WS[256 * 64];  // 32KB panel

  const int tid = threadIdx.x;
  const int w = tid >> 6, l = tid & 63, lr = l & 15, g = l >> 4;
  const floatx4 zf = {0.f, 0.f, 0.f, 0.f};
  const size_t token = (size_t)blockIdx.x * 64 + w * 16 + lr;

  floatx4 acc[16];
#pragma unroll
  for (int i = 0; i < 16; ++i) acc[i] = zf;

  short8 aA = *(const short8*)(ao + token * 256 + g * 8);
  short8 aB = *(const short8*)(ao + token * 256 + 32 + g * 8);
#pragma unroll
  for (int ph = 0; ph < 4; ++ph) {
    if (ph) __syncthreads();
    const short* src = wpk + ph * 16384;
#pragma unroll
    for (int i = 0; i < 8; ++i) {
      int ub = (i * 4 + w) * 64;
      gl2lds(src + (ub + l) * 8, WS + ub * 8);
    }
    __syncthreads();
    short8 nA, nB;
    if (ph < 3) {
      nA = *(const short8*)(ao + token * 256 + (ph + 1) * 64 + g * 8);
      nB = *(const short8*)(ao + token * 256 + (ph + 1) * 64 + 32 + g * 8);
    }
#pragma unroll
    for (int ct = 0; ct < 16; ++ct) {
      int rb = ct * 16 + lr;
      short8 b0 = *(const short8*)&WS[rb * 64 + ((g ^ (rb & 7)) << 3)];
      acc[ct] = MFMA16(b0, aA, acc[ct]);
      short8 b1 = *(const short8*)&WS[rb * 64 + (((4 + g) ^ (rb & 7)) << 3)];
      acc[ct] = MFMA16(b1, aB, acc[ct]);
    }
    aA = nA;
    aB = nB;
  }

  // epilogue: x = acc + pb + vin; LN2 (in-lane + g-group shfl); split stores
  float s1 = 0.f, s2 = 0.f;
#pragma unroll
  for (int ct = 0; ct < 16; ++ct) {
    float4 pb = *(const float4*)(proj_b + ct * 16 + 4 * g);
    float4 vv = *(const float4*)(vin + token * 256 + ct * 16 + 4 * g);
#pragma unroll
    for (int j = 0; j < 4; ++j) {
      float val = acc[ct][j] + ((const float*)&pb)[j] + ((const float*)&vv)[j];
      acc[ct][j] = val;
      s1 += val;
      s2 += val * val;
    }
  }
  s1 += __shfl_xor(s1, 16); s1 += __shfl_xor(s1, 32);
  s2 += __shfl_xor(s2, 16); s2 += __shfl_xor(s2, 32);
  float mean = s1 * (1.0f / 256.0f);
  float var = s2 * (1.0f / 256.0f) - mean * mean;
  float inv = rsqrtf(var + 1e-5f);
#pragma unroll
  for (int ct = 0; ct < 16; ++ct) {  // stream 1: xbf
    shortx4 xo;
#pragma unroll
    for (int j = 0; j < 4; ++j) xo[j] = f2bf(acc[ct][j]);
    *(shortx4*)(xbf + token * 256 + ct * 16 + 4 * g) = xo;
  }
#pragma unroll
  for (int ct = 0; ct < 16; ++ct) {  // stream 2: xln
    float4 gg = *(const float4*)(g2 + ct * 16 + 4 * g);
    float4 bb = *(const float4*)(b2 + ct * 16 + 4 * g);
    shortx4 lo;
#pragma unroll
    for (int j = 0; j < 4; ++j)
      lo[j] = f2bf((acc[ct][j] - mean) * inv * ((const float*)&gg)[j] + ((const float*)&bb)[j]);
    *(shortx4*)(xln + token * 256 + ct * 16 + 4 * g) = lo;
  }
}

// ---------------------------------------------------------------------------
// Kernel M1: mlp1 half + GELU. Grid (1024, 2) x 256 thr. 4 phases.
// ---------------------------------------------------------------------------
__global__ __launch_bounds__(256, 4) void mlp1_kernel(
    const short* __restrict__ xln, const short* __restrict__ w1k,
    const float* __restrict__ mb1, short* __restrict__ h1) {
  __shared__ short WS[256 * 64];

  const int tid = threadIdx.x;
  const int w = tid >> 6, l = tid & 63, lr = l & 15, g = l >> 4;
  const int hf = blockIdx.y;
  const floatx4 zf = {0.f, 0.f, 0.f, 0.f};
  const size_t token = (size_t)blockIdx.x * 64 + w * 16 + lr;
  const short* wph = w1k + (size_t)hf * 65536;

  floatx4 acc[16];
#pragma unroll
  for (int i = 0; i < 16; ++i) acc[i] = zf;

  short8 aA = *(const short8*)(xln + token * 256 + g * 8);
  short8 aB = *(const short8*)(xln + token * 256 + 32 + g * 8);
#pragma unroll
  for (int ph = 0; ph < 4; ++ph) {
    if (ph) __syncthreads();
    const short* src = wph + ph * 16384;
#pragma unroll
    for (int i = 0; i < 8; ++i) {
      int ub = (i * 4 + w) * 64;
      gl2lds(src + (ub + l) * 8, WS + ub * 8);
    }
    __syncthreads();
    short8 nA, nB;
    if (ph < 3) {
      nA = *(const short8*)(xln + token * 256 + (ph + 1) * 64 + g * 8);
      nB = *(const short8*)(xln + token * 256 + (ph + 1) * 64 + 32 + g * 8);
    }
#pragma unroll
    for (int ct = 0; ct < 16; ++ct) {
      int rb = ct * 16 + lr;
      short8 b0 = *(const short8*)&WS[rb * 64 + ((g ^ (rb & 7)) << 3)];
      acc[ct] = MFMA16(b0, aA, acc[ct]);
      short8 b1 = *(const short8*)&WS[rb * 64 + (((4 + g) ^ (rb & 7)) << 3)];
      acc[ct] = MFMA16(b1, aB, acc[ct]);
    }
    aA = nA;
    aB = nB;
  }

#pragma unroll
  for (int ct = 0; ct < 16; ++ct) {
    float4 bb = *(const float4*)(mb1 + hf * 256 + ct * 16 + 4 * g);
    shortx4 ho;
#pragma unroll
    for (int j = 0; j < 4; ++j) {
      float xv = acc[ct][j] + ((const float*)&bb)[j];
      float yy = 1.5957691216057308f * (xv + 0.044715f * xv * xv * xv);
      float sg = 1.0f / (1.0f + __expf(-yy));
      ho[j] = f2bf(xv * sg);
    }
    *(shortx4*)(h1 + token * 512 + hf * 256 + ct * 16 + 4 * g) = ho;
  }
}

// ---------------------------------------------------------------------------
// Kernel M2: mlp2 + bias + residual(xbf) -> out fp32. Grid 1024 x 256 thr.
// 8 phases over K=512; acc covers all 256 oc.
// ---------------------------------------------------------------------------
__global__ __launch_bounds__(256, 4) void mlp2_kernel(
    const short* __restrict__ h1, const short* __restrict__ w2k,
    const float* __restrict__ mb2, const short* __restrict__ xbf,
    float* __restrict__ out) {
  __shared__ short WS[256 * 64];

  const int tid = threadIdx.x;
  const int w = tid >> 6, l = tid & 63, lr = l & 15, g = l >> 4;
  const floatx4 zf = {0.f, 0.f, 0.f, 0.f};
  const size_t token = (size_t)blockIdx.x * 64 + w * 16 + lr;

  floatx4 acc[16];
#pragma unroll
  for (int i = 0; i < 16; ++i) acc[i] = zf;

  short8 aA = *(const short8*)(h1 + token * 512 + g * 8);
  short8 aB = *(const short8*)(h1 + token * 512 + 32 + g * 8);
#pragma unroll
  for (int ph = 0; ph < 8; ++ph) {
    if (ph) __syncthreads();
    const short* src = w2k + ph * 16384;
#pragma unroll
    for (int i = 0; i < 8; ++i) {
      int ub = (i * 4 + w) * 64;
      gl2lds(src + (ub + l) * 8, WS + ub * 8);
    }
    __syncthreads();
    short8 nA, nB;
    if (ph < 7) {
      nA = *(const short8*)(h1 + token * 512 + (ph + 1) * 64 + g * 8);
      nB = *(const short8*)(h1 + token * 512 + (ph + 1) * 64 + 32 + g * 8);
    }
#pragma unroll
    for (int ct = 0; ct < 16; ++ct) {
      int rb = ct * 16 + lr;
      short8 b0 = *(const short8*)&WS[rb * 64 + ((g ^ (rb & 7)) << 3)];
      acc[ct] = MFMA16(b0, aA, acc[ct]);
      short8 b1 = *(const short8*)&WS[rb * 64 + (((4 + g) ^ (rb & 7)) << 3)];
      acc[ct] = MFMA16(b1, aB, acc[ct]);
    }
    aA = nA;
    aB = nB;
  }

#pragma unroll
  for (int ct = 0; ct < 16; ++ct) {
    int oc = ct * 16 + 4 * g;
    float4 bb = *(const float4*)(mb2 + oc);
    shortx4 xb = *(const shortx4*)(xbf + token * 256 + oc);
    float4 o;
#pragma unroll
    for (int j = 0; j < 4; ++j)
      ((float*)&o)[j] = bf2f(xb[j]) + acc[ct][j] + ((const float*)&bb)[j];
    *(float4*)(out + token * 256 + oc) = o;
  }
}

// ---------------------------------------------------------------------------
extern "C" void kernel_launch(void* const* d_in, const int* in_sizes, int n_in,
                              void* d_out, int out_size, void* d_ws, size_t ws_size,
                              hipStream_t stream) {
  const float* q = (const float*)d_in[0];
  const float* k = (const float*)d_in[1];
  const float* v = (const float*)d_in[2];
  const float* gq = (const float*)d_in[3];
  const float* bq = (const float*)d_in[4];
  const float* gk = (const float*)d_in[5];
  const float* bk = (const float*)d_in[6];
  const float* gv = (const float*)d_in[7];
  const float* bv = (const float*)d_in[8];
  const float* bias_table = (const float*)d_in[9];
  const float* proj_w = (const float*)d_in[10];
  const float* proj_b = (const float*)d_in[11];
  const float* g2 = (const float*)d_in[12];
  const float* b2 = (const float*)d_in[13];
  const float* mw1 = (const float*)d_in[14];
  const float* mb1 = (const float*)d_in[15];
  const float* mw2 = (const float*)d_in[16];
  const float* mb2 = (const float*)d_in[17];

  char* ws = (char*)d_ws;
  short* qw = (short*)(ws + 0);
  short* kw = (short*)(ws + 33554432);
  short* vw = (short*)(ws + 67108864);
  short* ao = (short*)(ws + 100663296);
  short* xln = (short*)(ws + 0);         // over qw (dead after attn)
  short* xbf = (short*)(ws + 33554432);  // over kw (dead after attn)
  short* h1 = (short*)(ws + 67108864);   // over vw+ao (dead after attn / P)
  short* wpk = (short*)(ws + 167772160);
  short* w1k = (short*)(ws + 167903232);
  short* w2k = (short*)(ws + 168165376);
  short* biasPb = (short*)(ws + 168427520);

  packP_kernel<<<256, 256, 0, stream>>>(proj_w, wpk);
  pack1_kernel<<<512, 256, 0, stream>>>(mw1, w1k);
  pack2_kernel<<<512, 256, 0, stream>>>(mw2, w2k);
  biasprep_kernel<<<512, 256, 0, stream>>>(bias_table, biasPb);

  ln_qkv_kernel<<<dim3(8192, 3), 256, 0, stream>>>(q, k, v, gq, bq, gk, bk, gv, bv, qw, kw, vw);

  attn_kernel<<<dim3(512, 8), 256, 0, stream>>>(qw, kw, vw, biasPb, ao);

  projln_kernel<<<1024, 256, 0, stream>>>(ao, wpk, proj_b, v, g2, b2, xbf, xln);

  mlp1_kernel<<<dim3(1024, 2), 256, 0, stream>>>(xln, w1k, mb1, h1);

  mlp2_kernel<<<1024, 256, 0, stream>>>(h1, w2k, mb2, xbf, (float*)d_out);
}